// Round 5
// baseline (378.951 us; speedup 1.0000x reference)
//
#include <hip/hip_runtime.h>

// QueryAndGroup: ball_query(r=0.2, nsample=32) + group xyz (centered) + group features.
// B=4, N=16384, M=2048, C=64. Output (B, 67, M, 32) f32.
//
// Single kernel, block-role split:
//   blocks [0, 1024):    transpose feat (B,C,N) -> featT (B,N,C) in d_ws, then
//                        __threadfence + atomicAdd a done-counter.
//   blocks [1024, 3072): fused per-wave ball-query scan (double-buffered
//                        prefetch) -> centered-xyz writes -> bounded poll on the
//                        done-counter -> feature gather from featT (fast path)
//                        or directly from feat (fallback; identical values, so
//                        output is exact regardless of timing/dispatch order).
// This recovers R1's fused scan||gather wave-overlap AND hides the transpose
// under the scan instead of serializing it (R1) or splitting kernels (R2/R3).

#define WPB 4
constexpr int Bc = 4, Nc = 16384, Mc = 2048, Cc = 64, Sc = 32;
constexpr int TB = (Nc / 64) * Bc;       // 1024 transpose blocks
constexpr int SB = (Bc * Mc) / WPB;      // 2048 scan blocks

__global__ __launch_bounds__(256) void fused_kernel(
    const float* __restrict__ xyz,      // (B, N, 3)
    const float* __restrict__ new_xyz,  // (B, M, 3)
    const float* __restrict__ feat,     // (B, C, N)
    float* __restrict__ featT,          // (B, N, C) workspace
    unsigned int* __restrict__ done,    // zeroed before launch
    float* __restrict__ out)            // (B, 67, M, 32)
{
#pragma clang fp contract(off)
    __shared__ float tile[64][65];
    __shared__ int sidx[WPB][Sc];

    if (blockIdx.x < TB) {
        // ---------------- transpose role ----------------
        const int b = blockIdx.x >> 8;               // / (Nc/64)
        const int nbase = (blockIdx.x & 255) * 64;
        const int tn = threadIdx.x & 63;
        const int tq = threadIdx.x >> 6;             // 0..3
        const float* fb = feat + (size_t)b * Cc * Nc;
        float* ob = featT + (size_t)b * Nc * Cc;
        #pragma unroll
        for (int k = 0; k < 16; ++k) {
            const int c = k * 4 + tq;
            tile[tn][c] = fb[(size_t)c * Nc + nbase + tn];      // coalesced reads
        }
        __syncthreads();
        #pragma unroll
        for (int k = 0; k < 16; ++k) {
            const int nl = k * 4 + tq;
            ob[(size_t)(nbase + nl) * Cc + tn] = tile[nl][tn];  // coalesced writes
        }
        __syncthreads();   // waits vmcnt(0): all this block's stores complete
        if (threadIdx.x == 0) {
            __threadfence();                                    // device-scope release
            atomicAdd(done, 1u);
        }
        return;
    }

    // ---------------- scan + gather role ----------------
    const int sb   = blockIdx.x - TB;
    const int lane = threadIdx.x & 63;
    const int wv   = threadIdx.x >> 6;
    const int q    = sb * WPB + wv;
    const int b    = q >> 11;            // / Mc
    const int m    = q & (Mc - 1);

    const float r2 = 0.2f * 0.2f;
    const float* nz = new_xyz + (size_t)(b * Mc + m) * 3;
    const float qx = nz[0], qy = nz[1], qz = nz[2];
    const float* xb = xyz + (size_t)b * Nc * 3;

    int count = 0, firstIdx = 0;
    const unsigned long long lt = (1ull << lane) - 1ull;

    float px[4], py[4], pz[4];
    #pragma unroll
    for (int u = 0; u < 4; ++u) {
        const float* pp = xb + (size_t)(u * 64 + lane) * 3;
        px[u] = pp[0]; py[u] = pp[1]; pz[u] = pp[2];
    }
    for (int base = 0; base < Nc; base += 256) {
        const int nb = (base + 256 < Nc) ? base + 256 : base;   // prefetch next
        float nx[4], ny[4], nzv[4];
        #pragma unroll
        for (int u = 0; u < 4; ++u) {
            const float* pp = xb + (size_t)(nb + u * 64 + lane) * 3;
            nx[u] = pp[0]; ny[u] = pp[1]; nzv[u] = pp[2];
        }
        #pragma unroll
        for (int u = 0; u < 4; ++u) {
            const float dx = qx - px[u], dy = qy - py[u], dz = qz - pz[u];
            float d2 = dx * dx + dy * dy;   // no fma: match np/jax f32 rounding
            d2 = d2 + dz * dz;
            const bool in = d2 < r2;
            const unsigned long long mask = __ballot(in);
            if (in) {
                const int slot = count + __popcll(mask & lt);
                if (slot < Sc) sidx[wv][slot] = base + u * 64 + lane;
            }
            if (count == 0 && mask != 0ull)
                firstIdx = base + u * 64 + __builtin_ctzll(mask);
            count += __popcll(mask);
        }
        if (count >= Sc) break;             // wave-uniform
        #pragma unroll
        for (int u = 0; u < 4; ++u) { px[u] = nx[u]; py[u] = ny[u]; pz[u] = nzv[u]; }
    }
    {
        const int start = count < Sc ? count : Sc;
        if (start + lane < Sc) sidx[wv][start + lane] = firstIdx;
    }
    // Same-wave LDS visibility only (waves independent; no block barrier).
    asm volatile("s_waitcnt lgkmcnt(0)" ::: "memory");

    const int s     = lane & 31;
    const int chalf = lane >> 5;
    const int myid  = sidx[wv][s];
    float* ob = out + ((size_t)b * 67 * Mc + m) * Sc;

    // Centered-xyz channels 0..2 (no featT dependency -- do before polling).
    ob[(size_t)chalf * (Mc * Sc) + s] = xb[(size_t)myid * 3 + chalf] - (chalf ? qy : qx);
    if (chalf == 0)
        ob[(size_t)2 * (Mc * Sc) + s] = xb[(size_t)myid * 3 + 2] - qz;

    // Bounded wait for transpose completion (typically already done or soon).
    int fastflag = 0;
    if (lane == 0) {
        unsigned int v = 0;
        for (int it = 0; it < 4096; ++it) {
            v = __hip_atomic_load(done, __ATOMIC_ACQUIRE, __HIP_MEMORY_SCOPE_AGENT);
            if (v == (unsigned int)TB) break;
            __builtin_amdgcn_s_sleep(8);
        }
        fastflag = (v == (unsigned int)TB) ? 1 : 0;
    }
    fastflag = __shfl(fastflag, 0);

    if (fastflag) {
        __threadfence();   // acquire ordering for all lanes before featT reads
        // Fast path: contiguous 256B featT row per sample, 8 float4 loads/lane.
        const float* ftb = featT + ((size_t)b * Nc + myid) * Cc;
        #pragma unroll
        for (int it = 0; it < 8; ++it) {
            const int c4 = it * 2 + chalf;                  // 0..15
            const float4 v = *(const float4*)(ftb + c4 * 4);
            #pragma unroll
            for (int k = 0; k < 4; ++k)
                ob[(size_t)(3 + c4 * 4 + k) * (Mc * Sc) + s] = ((const float*)&v)[k];
        }
    } else {
        // Fallback (never in practice): direct (C,N) gather -- identical values.
        const float* fb = feat + (size_t)b * Cc * Nc;
        #pragma unroll
        for (int it = 0; it < 32; ++it) {
            const int c = it * 2 + chalf;
            ob[(size_t)(3 + c) * (Mc * Sc) + s] = fb[(size_t)c * Nc + myid];
        }
    }
}

// Fallback if ws too small (not expected): fused direct-gather kernel.
__global__ __launch_bounds__(256) void qg_fallback_kernel(
    const float* __restrict__ xyz, const float* __restrict__ new_xyz,
    const float* __restrict__ feat, float* __restrict__ out)
{
#pragma clang fp contract(off)
    const int lane = threadIdx.x & 63;
    const int wv   = threadIdx.x >> 6;
    const int q    = blockIdx.x * WPB + wv;
    const int b    = q >> 11;
    const int m    = q & (Mc - 1);
    __shared__ int sidx[WPB][Sc];
    const float r2 = 0.2f * 0.2f;
    const float* nz = new_xyz + (size_t)(b * Mc + m) * 3;
    const float qx = nz[0], qy = nz[1], qz = nz[2];
    const float* xb = xyz + (size_t)b * Nc * 3;
    int count = 0, firstIdx = 0;
    const unsigned long long lt = (1ull << lane) - 1ull;
    for (int base = 0; base < Nc; base += 64) {
        const int i = base + lane;
        const float px = xb[i * 3], py = xb[i * 3 + 1], pz = xb[i * 3 + 2];
        const float dx = qx - px, dy = qy - py, dz = qz - pz;
        float d2 = dx * dx + dy * dy; d2 = d2 + dz * dz;
        const bool in = d2 < r2;
        const unsigned long long mask = __ballot(in);
        if (in) {
            const int slot = count + __popcll(mask & lt);
            if (slot < Sc) sidx[wv][slot] = i;
        }
        if (count == 0 && mask != 0ull) firstIdx = base + __builtin_ctzll(mask);
        count += __popcll(mask);
        if (count >= Sc) break;
    }
    const int start = count < Sc ? count : Sc;
    if (start + lane < Sc) sidx[wv][start + lane] = firstIdx;
    asm volatile("s_waitcnt lgkmcnt(0)" ::: "memory");
    const int s = lane & 31, chalf = lane >> 5;
    const int myid = sidx[wv][s];
    float* ob = out + ((size_t)b * 67 * Mc + m) * Sc;
    ob[(size_t)chalf * (Mc * Sc) + s] = xb[(size_t)myid * 3 + chalf] - (chalf ? qy : qx);
    if (chalf == 0)
        ob[(size_t)2 * (Mc * Sc) + s] = xb[(size_t)myid * 3 + 2] - qz;
    const float* fb = feat + (size_t)b * Cc * Nc;
    #pragma unroll
    for (int it = 0; it < 32; ++it) {
        const int c = it * 2 + chalf;
        ob[(size_t)(3 + c) * (Mc * Sc) + s] = fb[(size_t)c * Nc + myid];
    }
}

extern "C" void kernel_launch(void* const* d_in, const int* in_sizes, int n_in,
                              void* d_out, int out_size, void* d_ws, size_t ws_size,
                              hipStream_t stream) {
    const float* xyz     = (const float*)d_in[0];
    const float* new_xyz = (const float*)d_in[1];
    const float* feat    = (const float*)d_in[2];
    float* out           = (float*)d_out;

    const size_t featT_bytes = (size_t)Bc * Nc * Cc * sizeof(float);  // 16.8 MB

    if (ws_size >= featT_bytes + 64) {
        float* featT = (float*)d_ws;
        unsigned int* done = (unsigned int*)((char*)d_ws + featT_bytes);
        hipMemsetAsync(done, 0, sizeof(unsigned int), stream);
        hipLaunchKernelGGL(fused_kernel, dim3(TB + SB), dim3(256), 0, stream,
                           xyz, new_xyz, feat, featT, done, out);
    } else {
        hipLaunchKernelGGL(qg_fallback_kernel, dim3(SB), dim3(256), 0, stream,
                           xyz, new_xyz, feat, out);
    }
}

// Round 6
// 36.799 us; speedup vs baseline: 10.2979x; 10.2979x over previous
//
#include <hip/hip_runtime.h>

// QueryAndGroup: ball_query(r=0.2, nsample=32) + group xyz (centered) + group features.
// B=4, N=16384, M=2048, C=64. Output (B, 67, M, 32) f32.
//
// Structure = R1 (best measured: 38.9us), one change: the ball-query scan is
// double-buffered -- group k+1's 12 loads are issued before processing group k,
// so the per-group dependent chain is max(load_latency, process) not the sum.
// R2/R3/R4 splits/syncs all regressed; the fused scan||gather wave overlap is
// the thing to preserve.
//
// Kernel 1: transpose feat (B,C,N) -> featT (B,N,C) in d_ws (coalesced both
//           sides via 64x64 LDS tile; 33.6 MB round trip ~= 5.5us, BW-bound).
// Kernel 2: one wave per query. Prefetched scan collects first-32 in-radius
//           indices (ballot/prefix-popcount, wave-uniform early exit), then
//           gathers: per sample one contiguous 256B featT row (8 float4/lane),
//           stores s-coalesced 128B segments per half-wave.

#define WPB 4
constexpr int Bc = 4, Nc = 16384, Mc = 2048, Cc = 64, Sc = 32;

__global__ __launch_bounds__(256) void transpose_kernel(
    const float* __restrict__ feat,  // (B, C, N)
    float* __restrict__ featT)       // (B, N, C)
{
    __shared__ float tile[64][65];
    const int b = blockIdx.y;
    const int nbase = blockIdx.x * 64;
    const int tn = threadIdx.x & 63;
    const int tq = threadIdx.x >> 6;  // 0..3
    const float* fb = feat + (size_t)b * Cc * Nc;
    float* ob = featT + (size_t)b * Nc * Cc;
    #pragma unroll
    for (int k = 0; k < 16; ++k) {
        const int c = k * 4 + tq;
        tile[tn][c] = fb[(size_t)c * Nc + nbase + tn];      // coalesced reads
    }
    __syncthreads();
    #pragma unroll
    for (int k = 0; k < 16; ++k) {
        const int nl = k * 4 + tq;
        ob[(size_t)(nbase + nl) * Cc + tn] = tile[nl][tn];  // coalesced writes
    }
}

__global__ __launch_bounds__(256) void qg_kernel(
    const float* __restrict__ xyz,      // (B, N, 3)
    const float* __restrict__ new_xyz,  // (B, M, 3)
    const float* __restrict__ feat,     // (B, C, N)
    const float* __restrict__ featT,    // (B, N, C) or unused if useT==0
    float* __restrict__ out,            // (B, 67, M, 32)
    int useT)
{
#pragma clang fp contract(off)
    const int lane = threadIdx.x & 63;
    const int wv   = threadIdx.x >> 6;
    const int q    = blockIdx.x * WPB + wv;
    const int b    = q >> 11;          // / Mc
    const int m    = q & (Mc - 1);

    __shared__ int sidx[WPB][Sc];

    const float r2 = 0.2f * 0.2f;
    const float* nz = new_xyz + (size_t)(b * Mc + m) * 3;
    const float qx = nz[0], qy = nz[1], qz = nz[2];
    const float* xb = xyz + (size_t)b * Nc * 3;

    int count = 0, firstIdx = 0;
    const unsigned long long lt = (1ull << lane) - 1ull;

    // Double-buffered scan: group k+1's loads in flight while processing k.
    float px[4], py[4], pz[4];
    #pragma unroll
    for (int u = 0; u < 4; ++u) {
        const float* pp = xb + (size_t)(u * 64 + lane) * 3;
        px[u] = pp[0]; py[u] = pp[1]; pz[u] = pp[2];
    }
    for (int base = 0; base < Nc; base += 256) {
        const int nb = (base + 256 < Nc) ? base + 256 : base;   // clamped prefetch
        float nx[4], ny[4], nzv[4];
        #pragma unroll
        for (int u = 0; u < 4; ++u) {
            const float* pp = xb + (size_t)(nb + u * 64 + lane) * 3;
            nx[u] = pp[0]; ny[u] = pp[1]; nzv[u] = pp[2];
        }
        #pragma unroll
        for (int u = 0; u < 4; ++u) {
            const float dx = qx - px[u], dy = qy - py[u], dz = qz - pz[u];
            float d2 = dx * dx + dy * dy;   // no fma: match np/jax f32 rounding
            d2 = d2 + dz * dz;
            const bool in = d2 < r2;
            const unsigned long long mask = __ballot(in);
            if (in) {
                const int slot = count + __popcll(mask & lt);
                if (slot < Sc) sidx[wv][slot] = base + u * 64 + lane;
            }
            if (count == 0 && mask != 0ull)
                firstIdx = base + u * 64 + __builtin_ctzll(mask);
            count += __popcll(mask);
        }
        if (count >= Sc) break;             // wave-uniform
        #pragma unroll
        for (int u = 0; u < 4; ++u) { px[u] = nx[u]; py[u] = ny[u]; pz[u] = nzv[u]; }
    }
    {
        const int start = count < Sc ? count : Sc;
        if (start + lane < Sc) sidx[wv][start + lane] = firstIdx;
    }
    // Same-wave LDS visibility only; waves stay decoupled (no block barrier).
    asm volatile("s_waitcnt lgkmcnt(0)" ::: "memory");

    const int s     = lane & 31;
    const int chalf = lane >> 5;
    const int myid  = sidx[wv][s];
    float* ob = out + ((size_t)b * 67 * Mc + m) * Sc;

    // Centered-xyz channels 0..2.
    ob[(size_t)chalf * (Mc * Sc) + s] = xb[(size_t)myid * 3 + chalf] - (chalf ? qy : qx);
    if (chalf == 0)
        ob[(size_t)2 * (Mc * Sc) + s] = xb[(size_t)myid * 3 + 2] - qz;

    if (useT) {
        // 256B-aligned featT row per sample: 8 float4 loads/lane.
        const float* ftb = featT + ((size_t)b * Nc + myid) * Cc;
        #pragma unroll
        for (int it = 0; it < 8; ++it) {
            const int c4 = it * 2 + chalf;                  // 0..15
            const float4 v = *(const float4*)(ftb + c4 * 4);
            #pragma unroll
            for (int k = 0; k < 4; ++k)
                ob[(size_t)(3 + c4 * 4 + k) * (Mc * Sc) + s] = ((const float*)&v)[k];
        }
    } else {
        // Fallback: direct (C,N) gather (identical values).
        const float* fb = feat + (size_t)b * Cc * Nc;
        #pragma unroll
        for (int it = 0; it < 32; ++it) {
            const int c = it * 2 + chalf;
            ob[(size_t)(3 + c) * (Mc * Sc) + s] = fb[(size_t)c * Nc + myid];
        }
    }
}

extern "C" void kernel_launch(void* const* d_in, const int* in_sizes, int n_in,
                              void* d_out, int out_size, void* d_ws, size_t ws_size,
                              hipStream_t stream) {
    const float* xyz     = (const float*)d_in[0];
    const float* new_xyz = (const float*)d_in[1];
    const float* feat    = (const float*)d_in[2];
    float* out           = (float*)d_out;

    const size_t needT = (size_t)Bc * Nc * Cc * sizeof(float);  // 16.8 MB
    float* featT = (float*)d_ws;
    const int useT = (ws_size >= needT) ? 1 : 0;

    if (useT) {
        dim3 g(Nc / 64, Bc);
        hipLaunchKernelGGL(transpose_kernel, g, dim3(256), 0, stream, feat, featT);
    }
    hipLaunchKernelGGL(qg_kernel, dim3((Bc * Mc) / WPB), dim3(256), 0, stream,
                       xyz, new_xyz, feat, featT, out, useT);
}